// Round 17
// baseline (192.202 us; speedup 1.0000x reference)
//
#include <hip/hip_runtime.h>
#include <stdint.h>

namespace {
constexpr int kH = 16;
constexpr int kS = 8192;
constexpr int kD = 64;
constexpr int kW = 1024;

typedef __attribute__((ext_vector_type(4)))  float float4_t;
typedef __attribute__((ext_vector_type(16))) float f32x16;
typedef __attribute__((ext_vector_type(8)))  short bf16x8;
typedef __attribute__((ext_vector_type(8)))  short short8_t;
typedef __attribute__((ext_vector_type(4)))  unsigned int u32x4;

__device__ __forceinline__ unsigned short f2bf(float f) {
    union { float fv; uint32_t u; } c; c.fv = f;
    return (unsigned short)((c.u + 0x7fffu + ((c.u >> 16) & 1u)) >> 16);
}

__device__ __forceinline__ float fexp2(float x) {
#if __has_builtin(__builtin_amdgcn_exp2f)
    return __builtin_amdgcn_exp2f(x);
#else
    return exp2f(x);
#endif
}

__device__ __forceinline__ void gload16(const void* g, char* l) {
    __builtin_amdgcn_global_load_lds(
        (const __attribute__((address_space(1))) void*)g,
        (__attribute__((address_space(3))) void*)l, 16, 0, 0);
}

// P^T f32[16] -> two bf16x8 B-fragments (verified cvt_pk + permlane order)
#define P_TO_FRAGS(P, U0, U1)                                                            \
    {                                                                                    \
        unsigned int wrd[8];                                                             \
        _Pragma("unroll")                                                                \
        for (int j = 0; j < 8; ++j)                                                      \
            asm("v_cvt_pk_bf16_f32 %0, %1, %2" : "=v"(wrd[j]) : "v"(P[2*j]), "v"(P[2*j+1])); \
        asm("v_permlane32_swap_b32 %0, %1" : "+v"(wrd[0]), "+v"(wrd[2]));                \
        asm("v_permlane32_swap_b32 %0, %1" : "+v"(wrd[1]), "+v"(wrd[3]));                \
        asm("v_permlane32_swap_b32 %0, %1" : "+v"(wrd[4]), "+v"(wrd[6]));                \
        asm("v_permlane32_swap_b32 %0, %1" : "+v"(wrd[5]), "+v"(wrd[7]));                \
        U0.u[0] = wrd[0]; U0.u[1] = wrd[1]; U0.u[2] = wrd[2]; U0.u[3] = wrd[3];          \
        U1.u[0] = wrd[4]; U1.u[1] = wrd[5]; U1.u[2] = wrd[6]; U1.u[3] = wrd[7];          \
    }

// ---- prepass (V only): fp32 [S][D] -> bf16 V^T [D][S] per head ----
__global__ __launch_bounds__(256)
void prep_v(const float* __restrict__ V, unsigned short* __restrict__ Vt) {
    __shared__ float tile[64][65];
    const int h  = blockIdx.y;
    const int s0 = blockIdx.x * 64;
    const int tid = threadIdx.x;
    const size_t hb = (size_t)h * kS * kD;
    #pragma unroll
    for (int it = 0; it < 4; ++it) {
        const int n = tid + it * 256;
        const int s = n >> 4, d0 = (n & 15) * 4;
        float4_t v = *(const float4_t*)(V + hb + (size_t)(s0 + s) * kD + d0);
        tile[s][d0 + 0] = v[0]; tile[s][d0 + 1] = v[1];
        tile[s][d0 + 2] = v[2]; tile[s][d0 + 3] = v[3];
    }
    __syncthreads();
    #pragma unroll
    for (int it = 0; it < 2; ++it) {
        const int n = tid + it * 256;
        const int d = n >> 3, sc = (n & 7) * 8;
        short8_t o;
        #pragma unroll
        for (int j = 0; j < 8; ++j) o[j] = (short)f2bf(tile[sc + j][d]);
        *(short8_t*)(Vt + hb + (size_t)d * kS + s0 + sc) = o;
    }
}

// ---- main: R14 skeleton; K staged fp32->reg->cvt->swizzled ds_write in-kernel ----
__global__ __launch_bounds__(256, 4)
void swa_main(const float* __restrict__ Qg, const float* __restrict__ Kg,
              const unsigned short* __restrict__ Vt, float* __restrict__ Og) {
    // per buffer: [0,8K) K tile [64 keys][128B] XOR-swz, [8K,16K) V^T tile
    __shared__ __align__(16) char lds[2][16384];

    const int lid  = blockIdx.x;                      // 0..1023
    const int swz  = (lid & 7) * 128 + (lid >> 3);    // XCD-chunked, bijective
    const int h    = swz >> 6;
    const int qblk = swz & 63;

    const int tid  = threadIdx.x;
    const int wv   = tid >> 6;
    const int lane = tid & 63;
    const int lq   = lane & 31;
    const int hi   = lane >> 5;

    const int q0b = qblk * 128;
    const int qs  = q0b + wv * 32;
    const int q   = qs + lq;
    const size_t hb = (size_t)h * kS * kD;

    constexpr float qscale = 0.125f * 1.44269504f;
    bf16x8 qf[4];
    {
        const float* qp = Qg + hb + (size_t)q * kD + hi * 8;
        #pragma unroll
        for (int c = 0; c < 4; ++c) {
            float4_t a = *(const float4_t*)(qp + c * 16);
            float4_t b = *(const float4_t*)(qp + c * 16 + 4);
            bf16x8 f;
            #pragma unroll
            for (int j = 0; j < 4; ++j) {
                f[j]     = (short)f2bf(a[j] * qscale);
                f[j + 4] = (short)f2bf(b[j] * qscale);
            }
            qf[c] = f;
        }
    }

    f32x16 acc[2];
    #pragma unroll
    for (int r = 0; r < 16; ++r) { acc[0][r] = 0.f; acc[1][r] = 0.f; }
    float l4[4] = {0.f, 0.f, 0.f, 0.f};

    const int kstart = (q0b >= kW) ? q0b - kW : 0;
    const int nt     = (q0b + 128 - kstart) >> 6;

    // ---- K staging (in-main convert): this thread's 2 chunks ----
    // chunk n: key r = n>>3, granule g = n&7; fp32 src K[kb+r][g*8..g*8+7]
    // dst byte = (r*128 + g*16) ^ ((r&7)<<4)   (R14 read-side swizzle)
    int kdst[2];
    const int r0 = tid >> 3, g0 = tid & 7;            // chunk tid
    const int r1 = (tid + 256) >> 3, g1 = tid & 7;    // chunk tid+256
    kdst[0] = (r0 * 128 + g0 * 16) ^ ((r0 & 7) << 4);
    kdst[1] = (r1 * 128 + g1 * 16) ^ ((r1 & 7) << 4);
    const float* KgH = Kg + hb;

    // V staging: dest chunk n linear; src chunk c = n ^ ((n>>3)&7)
    int srcV[2];
    #pragma unroll
    for (int i = 0; i < 2; ++i) {
        const int n = tid + i * 256;
        const int c = n ^ ((n >> 3) & 7);
        srcV[i] = (c >> 3) * kS + (c & 7) * 8;
    }
    const unsigned short* VtH = Vt + hb;

    float4_t kreg[2][2];   // [chunk][half of 8 floats]
    auto loadK = [&](int kb) {
        const float* p0 = KgH + (size_t)(kb + r0) * kD + g0 * 8;
        const float* p1 = KgH + (size_t)(kb + r1) * kD + g1 * 8;
        kreg[0][0] = *(const float4_t*)(p0);
        kreg[0][1] = *(const float4_t*)(p0 + 4);
        kreg[1][0] = *(const float4_t*)(p1);
        kreg[1][1] = *(const float4_t*)(p1 + 4);
    };
    auto stageV = [&](int buf, int kb) {
        const unsigned short* Vq = VtH + kb;
        #pragma unroll
        for (int i = 0; i < 2; ++i)
            gload16(Vq + srcV[i], &lds[buf][8192 + i * 4096 + wv * 1024]);
    };
    auto cvtWriteK = [&](int buf) {
        #pragma unroll
        for (int i = 0; i < 2; ++i) {
            u32x4 w;
            #pragma unroll
            for (int j = 0; j < 2; ++j) {
                unsigned int lo, hi2;
                asm("v_cvt_pk_bf16_f32 %0, %1, %2" : "=v"(lo)
                    : "v"(kreg[i][j][0]), "v"(kreg[i][j][1]));
                asm("v_cvt_pk_bf16_f32 %0, %1, %2" : "=v"(hi2)
                    : "v"(kreg[i][j][2]), "v"(kreg[i][j][3]));
                w[j * 2]     = lo;
                w[j * 2 + 1] = hi2;
            }
            *(u32x4*)(&lds[buf][kdst[i]]) = w;
        }
    };

    union U { unsigned int u[4]; bf16x8 v; };

    // ---- prologue: tile 0 ----
    loadK(kstart);                                    // 4 vmem -> regs
    stageV(0, kstart);                                // 2 gload_lds
    asm volatile("s_waitcnt vmcnt(2)" ::: "memory");  // K regs arrived
    cvtWriteK(0);

    for (int t = 0; t < nt; ++t) {
        const int kb  = kstart + t * 64;
        const int kbn = (t + 1 < nt) ? kb + 64 : kb;
        loadK(kbn);                                   // 4 vmem (tile t+1)
        stageV((t + 1) & 1, kbn);                     // 2 gload_lds (tile t+1)
        // drain tile t's V gloads (oldest 2) + my K ds_writes; keep t+1's 6 in flight
        asm volatile("s_waitcnt vmcnt(6) lgkmcnt(0)" ::: "memory");
        __builtin_amdgcn_s_barrier();
        asm volatile("" ::: "memory");

        const char* Kl = lds[t & 1];
        const char* Vl = lds[t & 1] + 8192;
        const int ksw = (lq & 7) << 4;

        const bool fast = (kb >= qs - 992) && (kb + 32 <= qs - 32);

        if (fast) {
            bf16x8 kf0[4], kf1[4], vf0[4], vf1[4];
            #pragma unroll
            for (int c = 0; c < 4; ++c) {
                kf0[c] = *(const bf16x8*)(Kl + ((lq * 128        + c * 32 + hi * 16) ^ ksw));
                kf1[c] = *(const bf16x8*)(Kl + (((32 + lq) * 128 + c * 32 + hi * 16) ^ ksw));
            }
            #pragma unroll
            for (int dh = 0; dh < 2; ++dh)
                #pragma unroll
                for (int kc = 0; kc < 2; ++kc) {
                    vf0[dh * 2 + kc] = *(const bf16x8*)(
                        Vl + (((dh * 32 + lq) * 128 + kc * 32 + hi * 16) ^ ksw));
                    vf1[dh * 2 + kc] = *(const bf16x8*)(
                        Vl + (((dh * 32 + lq) * 128 + 64 + kc * 32 + hi * 16) ^ ksw));
                }

            f32x16 st0, st1;
            #pragma unroll
            for (int r = 0; r < 16; ++r) { st0[r] = 0.f; st1[r] = 0.f; }
            #pragma unroll
            for (int c = 0; c < 4; ++c) {
                st0 = __builtin_amdgcn_mfma_f32_32x32x16_bf16(kf0[c], qf[c], st0, 0, 0, 0);
                st1 = __builtin_amdgcn_mfma_f32_32x32x16_bf16(kf1[c], qf[c], st1, 0, 0, 0);
            }

            float p0[16], p1[16];
            #pragma unroll
            for (int r = 0; r < 16; ++r) { p0[r] = fexp2(st0[r]); p1[r] = fexp2(st1[r]); }
            #pragma unroll
            for (int r = 0; r < 16; ++r) l4[r & 3] += p0[r] + p1[r];

            U a00, a01, a10, a11;
            P_TO_FRAGS(p0, a00, a01);
            P_TO_FRAGS(p1, a10, a11);

            acc[0] = __builtin_amdgcn_mfma_f32_32x32x16_bf16(vf0[0], a00.v, acc[0], 0, 0, 0);
            acc[1] = __builtin_amdgcn_mfma_f32_32x32x16_bf16(vf0[2], a00.v, acc[1], 0, 0, 0);
            acc[0] = __builtin_amdgcn_mfma_f32_32x32x16_bf16(vf0[1], a01.v, acc[0], 0, 0, 0);
            acc[1] = __builtin_amdgcn_mfma_f32_32x32x16_bf16(vf0[3], a01.v, acc[1], 0, 0, 0);
            acc[0] = __builtin_amdgcn_mfma_f32_32x32x16_bf16(vf1[0], a10.v, acc[0], 0, 0, 0);
            acc[1] = __builtin_amdgcn_mfma_f32_32x32x16_bf16(vf1[2], a10.v, acc[1], 0, 0, 0);
            acc[0] = __builtin_amdgcn_mfma_f32_32x32x16_bf16(vf1[1], a11.v, acc[0], 0, 0, 0);
            acc[1] = __builtin_amdgcn_mfma_f32_32x32x16_bf16(vf1[3], a11.v, acc[1], 0, 0, 0);
        } else {
            #pragma unroll
            for (int half = 0; half < 2; ++half) {
                const int kh = kb + half * 32;
                if (kh <= qs && kh >= qs - kW) {
                    const int krow = half * 32 + lq;
                    bf16x8 kf[4];
                    #pragma unroll
                    for (int c = 0; c < 4; ++c)
                        kf[c] = *(const bf16x8*)(Kl + ((krow * 128 + c * 32 + hi * 16) ^ ksw));

                    f32x16 st;
                    #pragma unroll
                    for (int r = 0; r < 16; ++r) st[r] = 0.f;
                    __builtin_amdgcn_s_setprio(1);
                    #pragma unroll
                    for (int c = 0; c < 4; ++c)
                        st = __builtin_amdgcn_mfma_f32_32x32x16_bf16(kf[c], qf[c], st, 0, 0, 0);
                    __builtin_amdgcn_s_setprio(0);

                    bf16x8 vf[4];
                    #pragma unroll
                    for (int dh = 0; dh < 2; ++dh)
                        #pragma unroll
                        for (int kc = 0; kc < 2; ++kc)
                            vf[dh * 2 + kc] = *(const bf16x8*)(
                                Vl + (((dh * 32 + lq) * 128 + half * 64 + kc * 32 + hi * 16) ^ ksw));

                    float p[16];
                    #pragma unroll
                    for (int r = 0; r < 16; ++r) {
                        const int ki = kh + (r & 3) + 8 * (r >> 2) + 4 * hi;
                        const bool ok = (ki <= q) && (ki + kW >= q);
                        const float e = fexp2(st[r]);
                        p[r] = ok ? e : 0.f;
                    }
                    #pragma unroll
                    for (int r = 0; r < 16; ++r) l4[r & 3] += p[r];

                    U u0, u1;
                    P_TO_FRAGS(p, u0, u1);

                    __builtin_amdgcn_s_setprio(1);
                    acc[0] = __builtin_amdgcn_mfma_f32_32x32x16_bf16(vf[0], u0.v, acc[0], 0, 0, 0);
                    acc[1] = __builtin_amdgcn_mfma_f32_32x32x16_bf16(vf[2], u0.v, acc[1], 0, 0, 0);
                    acc[0] = __builtin_amdgcn_mfma_f32_32x32x16_bf16(vf[1], u1.v, acc[0], 0, 0, 0);
                    acc[1] = __builtin_amdgcn_mfma_f32_32x32x16_bf16(vf[3], u1.v, acc[1], 0, 0, 0);
                    __builtin_amdgcn_s_setprio(0);
                }
            }
        }

        // K regs for tile t+1 arrived (issued a full tile ago); convert + write
        asm volatile("s_waitcnt vmcnt(2)" ::: "memory");
        cvtWriteK((t + 1) & 1);

        asm volatile("" ::: "memory");
        __builtin_amdgcn_s_barrier();                 // buf fully read before rewrite
        asm volatile("" ::: "memory");
    }

    // ---- epilogue ----
    float l = (l4[0] + l4[1]) + (l4[2] + l4[3]);
    l += __shfl_xor(l, 32);
    const float rl = 1.f / l;
    float* op = Og + hb + (size_t)q * kD;
    #pragma unroll
    for (int g = 0; g < 4; ++g) {
        float4_t o0, o1;
        #pragma unroll
        for (int j = 0; j < 4; ++j) {
            o0[j] = acc[0][g * 4 + j] * rl;
            o1[j] = acc[1][g * 4 + j] * rl;
        }
        *(float4_t*)(op + g * 8 + hi * 4)      = o0;
        *(float4_t*)(op + 32 + g * 8 + hi * 4) = o1;
    }
}
} // namespace

extern "C" void kernel_launch(void* const* d_in, const int* in_sizes, int n_in,
                              void* d_out, int out_size, void* d_ws, size_t ws_size,
                              hipStream_t stream) {
    (void)in_sizes; (void)n_in; (void)out_size; (void)ws_size;
    const float* Q = (const float*)d_in[0];
    const float* K = (const float*)d_in[1];
    const float* V = (const float*)d_in[2];
    float* O = (float*)d_out;
    unsigned short* Vt = (unsigned short*)d_ws;

    prep_v<<<dim3(kS / 64, kH), dim3(256), 0, stream>>>(V, Vt);
    swa_main<<<dim3(1024), dim3(256), 0, stream>>>(Q, K, Vt, O);
}

// Round 18
// 79.373 us; speedup vs baseline: 2.4215x; 2.4215x over previous
//
#include <hip/hip_runtime.h>
#include <stdint.h>

namespace {
constexpr int kH = 16;
constexpr int kS = 8192;
constexpr int kD = 64;
constexpr int kW = 1024;

typedef __attribute__((ext_vector_type(4)))  float float4_t;
typedef __attribute__((ext_vector_type(16))) float f32x16;
typedef __attribute__((ext_vector_type(8)))  short bf16x8;
typedef __attribute__((ext_vector_type(8)))  short short8_t;
typedef __attribute__((ext_vector_type(4)))  unsigned int u32x4;

__device__ __forceinline__ unsigned short f2bf(float f) {
    union { float fv; uint32_t u; } c; c.fv = f;
    return (unsigned short)((c.u + 0x7fffu + ((c.u >> 16) & 1u)) >> 16);
}

__device__ __forceinline__ float fexp2(float x) {
#if __has_builtin(__builtin_amdgcn_exp2f)
    return __builtin_amdgcn_exp2f(x);
#else
    return exp2f(x);
#endif
}

__device__ __forceinline__ void gload16(const void* g, char* l) {
    __builtin_amdgcn_global_load_lds(
        (const __attribute__((address_space(1))) void*)g,
        (__attribute__((address_space(3))) void*)l, 16, 0, 0);
}

// P^T f32[16] -> two bf16x8 B-fragments (verified cvt_pk + permlane order)
#define P_TO_FRAGS(P, U0, U1)                                                            \
    {                                                                                    \
        unsigned int wrd[8];                                                             \
        _Pragma("unroll")                                                                \
        for (int j = 0; j < 8; ++j)                                                      \
            asm("v_cvt_pk_bf16_f32 %0, %1, %2" : "=v"(wrd[j]) : "v"(P[2*j]), "v"(P[2*j+1])); \
        asm("v_permlane32_swap_b32 %0, %1" : "+v"(wrd[0]), "+v"(wrd[2]));                \
        asm("v_permlane32_swap_b32 %0, %1" : "+v"(wrd[1]), "+v"(wrd[3]));                \
        asm("v_permlane32_swap_b32 %0, %1" : "+v"(wrd[4]), "+v"(wrd[6]));                \
        asm("v_permlane32_swap_b32 %0, %1" : "+v"(wrd[5]), "+v"(wrd[7]));                \
        U0.u[0] = wrd[0]; U0.u[1] = wrd[1]; U0.u[2] = wrd[2]; U0.u[3] = wrd[3];          \
        U1.u[0] = wrd[4]; U1.u[1] = wrd[5]; U1.u[2] = wrd[6]; U1.u[3] = wrd[7];          \
    }

// ---- prepass (V only): fp32 [S][D] -> bf16 V^T [D][S] per head ----
__global__ __launch_bounds__(256)
void prep_v(const float* __restrict__ V, unsigned short* __restrict__ Vt) {
    __shared__ float tile[64][65];
    const int h  = blockIdx.y;
    const int s0 = blockIdx.x * 64;
    const int tid = threadIdx.x;
    const size_t hb = (size_t)h * kS * kD;
    #pragma unroll
    for (int it = 0; it < 4; ++it) {
        const int n = tid + it * 256;
        const int s = n >> 4, d0 = (n & 15) * 4;
        float4_t v = *(const float4_t*)(V + hb + (size_t)(s0 + s) * kD + d0);
        tile[s][d0 + 0] = v[0]; tile[s][d0 + 1] = v[1];
        tile[s][d0 + 2] = v[2]; tile[s][d0 + 3] = v[3];
    }
    __syncthreads();
    #pragma unroll
    for (int it = 0; it < 2; ++it) {
        const int n = tid + it * 256;
        const int d = n >> 3, sc = (n & 7) * 8;
        short8_t o;
        #pragma unroll
        for (int j = 0; j < 8; ++j) o[j] = (short)f2bf(tile[sc + j][d]);
        *(short8_t*)(Vt + hb + (size_t)d * kS + s0 + sc) = o;
    }
}

// ---- main: R6 compute body; K staged fp32->reg->cvt->swizzled ds_write ----
__global__ __launch_bounds__(256, 4)
void swa_main(const float* __restrict__ Qg, const float* __restrict__ Kg,
              const unsigned short* __restrict__ Vt, float* __restrict__ Og) {
    // per buffer: [0,8K) K tile [64 keys][128B] XOR-swz, [8K,16K) V^T tile
    __shared__ __align__(16) char lds[2][16384];

    const int lid  = blockIdx.x;                      // 0..1023
    const int swz  = (lid & 7) * 128 + (lid >> 3);    // XCD-chunked, bijective
    const int h    = swz >> 6;
    const int qblk = swz & 63;

    const int tid  = threadIdx.x;
    const int wv   = tid >> 6;
    const int lane = tid & 63;
    const int lq   = lane & 31;
    const int hi   = lane >> 5;

    const int q0b = qblk * 128;
    const int qs  = q0b + wv * 32;
    const int q   = qs + lq;
    const size_t hb = (size_t)h * kS * kD;

    constexpr float qscale = 0.125f * 1.44269504f;
    bf16x8 qf[4];
    {
        const float* qp = Qg + hb + (size_t)q * kD + hi * 8;
        #pragma unroll
        for (int c = 0; c < 4; ++c) {
            float4_t a = *(const float4_t*)(qp + c * 16);
            float4_t b = *(const float4_t*)(qp + c * 16 + 4);
            bf16x8 f;
            #pragma unroll
            for (int j = 0; j < 4; ++j) {
                f[j]     = (short)f2bf(a[j] * qscale);
                f[j + 4] = (short)f2bf(b[j] * qscale);
            }
            qf[c] = f;
        }
    }

    f32x16 acc[2];
    #pragma unroll
    for (int r = 0; r < 16; ++r) { acc[0][r] = 0.f; acc[1][r] = 0.f; }
    float l4[4] = {0.f, 0.f, 0.f, 0.f};

    const int kstart = (q0b >= kW) ? q0b - kW : 0;
    const int nt     = (q0b + 128 - kstart) >> 6;

    // K staging addresses: chunk n -> key r=n>>3, granule g=n&7 (8 fp32 = 16B bf16)
    const int r0 = tid >> 3, g8 = (tid & 7) * 8;      // chunk tid
    const int r1 = r0 + 32;                           // chunk tid+256
    const int kdst0 = (r0 * 128 + g8 * 2) ^ ((r0 & 7) << 4);
    const int kdst1 = (r1 * 128 + g8 * 2) ^ ((r1 & 7) << 4);
    const float* KgH = Kg + hb;

    // V staging: dest chunk n linear; src chunk c = n ^ ((n>>3)&7)
    int srcV[2];
    #pragma unroll
    for (int i = 0; i < 2; ++i) {
        const int n = tid + i * 256;
        const int c = n ^ ((n >> 3) & 7);
        srcV[i] = (c >> 3) * kS + (c & 7) * 8;
    }
    const unsigned short* VtH = Vt + hb;

    float4_t k0lo, k0hi, k1lo, k1hi;                  // named K fp32 regs

    union U { unsigned int u[4]; bf16x8 v; };

#define LOAD_K(KB)                                                         \
    {                                                                      \
        const float* p0_ = KgH + (size_t)((KB) + r0) * kD + g8;            \
        const float* p1_ = KgH + (size_t)((KB) + r1) * kD + g8;            \
        k0lo = *(const float4_t*)(p0_);                                    \
        k0hi = *(const float4_t*)(p0_ + 4);                                \
        k1lo = *(const float4_t*)(p1_);                                    \
        k1hi = *(const float4_t*)(p1_ + 4);                                \
    }

#define STAGE_V(BUF, KB)                                                   \
    {                                                                      \
        const unsigned short* vq_ = VtH + (KB);                            \
        gload16(vq_ + srcV[0], &lds[BUF][8192 + wv * 1024]);               \
        gload16(vq_ + srcV[1], &lds[BUF][8192 + 4096 + wv * 1024]);        \
    }

#define CVT_WRITE_K(BUF)                                                   \
    {                                                                      \
        unsigned int w0_, w1_, w2_, w3_;                                   \
        u32x4 wv0_, wv1_;                                                  \
        asm("v_cvt_pk_bf16_f32 %0, %1, %2" : "=v"(w0_) : "v"(k0lo[0]), "v"(k0lo[1])); \
        asm("v_cvt_pk_bf16_f32 %0, %1, %2" : "=v"(w1_) : "v"(k0lo[2]), "v"(k0lo[3])); \
        asm("v_cvt_pk_bf16_f32 %0, %1, %2" : "=v"(w2_) : "v"(k0hi[0]), "v"(k0hi[1])); \
        asm("v_cvt_pk_bf16_f32 %0, %1, %2" : "=v"(w3_) : "v"(k0hi[2]), "v"(k0hi[3])); \
        wv0_[0] = w0_; wv0_[1] = w1_; wv0_[2] = w2_; wv0_[3] = w3_;        \
        asm("v_cvt_pk_bf16_f32 %0, %1, %2" : "=v"(w0_) : "v"(k1lo[0]), "v"(k1lo[1])); \
        asm("v_cvt_pk_bf16_f32 %0, %1, %2" : "=v"(w1_) : "v"(k1lo[2]), "v"(k1lo[3])); \
        asm("v_cvt_pk_bf16_f32 %0, %1, %2" : "=v"(w2_) : "v"(k1hi[0]), "v"(k1hi[1])); \
        asm("v_cvt_pk_bf16_f32 %0, %1, %2" : "=v"(w3_) : "v"(k1hi[2]), "v"(k1hi[3])); \
        wv1_[0] = w0_; wv1_[1] = w1_; wv1_[2] = w2_; wv1_[3] = w3_;        \
        *(u32x4*)(&lds[BUF][kdst0]) = wv0_;                                \
        *(u32x4*)(&lds[BUF][kdst1]) = wv1_;                                \
    }

    // ---- prologue: tile 0 ----
    LOAD_K(kstart);
    STAGE_V(0, kstart);
    asm volatile("s_waitcnt vmcnt(2)" ::: "memory");  // K regs arrived; V flying
    CVT_WRITE_K(0);

    for (int t = 0; t < nt; ++t) {
        const int kb  = kstart + t * 64;
        const int kbn = (t + 1 < nt) ? kb + 64 : kb;
        LOAD_K(kbn);                                  // 4 vmem (tile t+1)
        STAGE_V((t + 1) & 1, kbn);                    // 2 gload_lds (tile t+1)
        // drain prior-tile V gloads + my K ds_writes; keep this iter's 6 in flight
        asm volatile("s_waitcnt vmcnt(6) lgkmcnt(0)" ::: "memory");
        __builtin_amdgcn_s_barrier();
        asm volatile("" ::: "memory");

        const char* Kl = lds[t & 1];
        const char* Vl = lds[t & 1] + 8192;
        const int ksw = (lq & 7) << 4;

        #pragma unroll
        for (int half = 0; half < 2; ++half) {
            const int kh = kb + half * 32;
            if (kh <= qs && kh >= qs - kW) {          // wave-uniform active check
                const int krow = half * 32 + lq;
                bf16x8 kf[4];
                #pragma unroll
                for (int c = 0; c < 4; ++c)
                    kf[c] = *(const bf16x8*)(Kl + ((krow * 128 + c * 32 + hi * 16) ^ ksw));

                f32x16 st;
                #pragma unroll
                for (int r = 0; r < 16; ++r) st[r] = 0.f;
                __builtin_amdgcn_s_setprio(1);
                #pragma unroll
                for (int c = 0; c < 4; ++c)
                    st = __builtin_amdgcn_mfma_f32_32x32x16_bf16(kf[c], qf[c], st, 0, 0, 0);
                __builtin_amdgcn_s_setprio(0);

                bf16x8 vf[4];
                #pragma unroll
                for (int dh = 0; dh < 2; ++dh)
                    #pragma unroll
                    for (int kc = 0; kc < 2; ++kc)
                        vf[dh * 2 + kc] = *(const bf16x8*)(
                            Vl + (((dh * 32 + lq) * 128 + half * 64 + kc * 32 + hi * 16) ^ ksw));

                float p[16];
                const bool interior = (kh <= qs - 32) && (kh >= qs - 992);
                if (interior) {
                    #pragma unroll
                    for (int r = 0; r < 16; ++r) p[r] = fexp2(st[r]);
                } else {
                    #pragma unroll
                    for (int r = 0; r < 16; ++r) {
                        const int ki = kh + (r & 3) + 8 * (r >> 2) + 4 * hi;
                        const bool ok = (ki <= q) && (ki + kW >= q);
                        const float e = fexp2(st[r]);
                        p[r] = ok ? e : 0.f;
                    }
                }
                #pragma unroll
                for (int r = 0; r < 16; ++r) l4[r & 3] += p[r];

                U u0, u1;
                P_TO_FRAGS(p, u0, u1);

                __builtin_amdgcn_s_setprio(1);
                acc[0] = __builtin_amdgcn_mfma_f32_32x32x16_bf16(vf[0], u0.v, acc[0], 0, 0, 0);
                acc[1] = __builtin_amdgcn_mfma_f32_32x32x16_bf16(vf[2], u0.v, acc[1], 0, 0, 0);
                acc[0] = __builtin_amdgcn_mfma_f32_32x32x16_bf16(vf[1], u1.v, acc[0], 0, 0, 0);
                acc[1] = __builtin_amdgcn_mfma_f32_32x32x16_bf16(vf[3], u1.v, acc[1], 0, 0, 0);
                __builtin_amdgcn_s_setprio(0);
            }
        }

        // K fp32 regs for tile t+1 arrived (full tile of cover); convert + write
        asm volatile("s_waitcnt vmcnt(2)" ::: "memory");
        CVT_WRITE_K((t + 1) & 1);

        asm volatile("" ::: "memory");
        __builtin_amdgcn_s_barrier();                 // buf fully read before rewrite
        asm volatile("" ::: "memory");
    }

    // ---- epilogue ----
    float l = (l4[0] + l4[1]) + (l4[2] + l4[3]);
    l += __shfl_xor(l, 32);
    const float rl = 1.f / l;
    float* op = Og + hb + (size_t)q * kD;
    #pragma unroll
    for (int g = 0; g < 4; ++g) {
        float4_t o0, o1;
        #pragma unroll
        for (int j = 0; j < 4; ++j) {
            o0[j] = acc[0][g * 4 + j] * rl;
            o1[j] = acc[1][g * 4 + j] * rl;
        }
        *(float4_t*)(op + g * 8 + hi * 4)      = o0;
        *(float4_t*)(op + 32 + g * 8 + hi * 4) = o1;
    }
#undef LOAD_K
#undef STAGE_V
#undef CVT_WRITE_K
}
} // namespace

extern "C" void kernel_launch(void* const* d_in, const int* in_sizes, int n_in,
                              void* d_out, int out_size, void* d_ws, size_t ws_size,
                              hipStream_t stream) {
    (void)in_sizes; (void)n_in; (void)out_size; (void)ws_size;
    const float* Q = (const float*)d_in[0];
    const float* K = (const float*)d_in[1];
    const float* V = (const float*)d_in[2];
    float* O = (float*)d_out;
    unsigned short* Vt = (unsigned short*)d_ws;

    prep_v<<<dim3(kS / 64, kH), dim3(256), 0, stream>>>(V, Vt);
    swa_main<<<dim3(1024), dim3(256), 0, stream>>>(Q, K, Vt, O);
}

// Round 19
// 70.581 us; speedup vs baseline: 2.7232x; 1.1246x over previous
//
#include <hip/hip_runtime.h>
#include <stdint.h>

namespace {
constexpr int kH = 16;
constexpr int kS = 8192;
constexpr int kD = 64;
constexpr int kW = 1024;

typedef __attribute__((ext_vector_type(4)))  float float4_t;
typedef __attribute__((ext_vector_type(16))) float f32x16;
typedef __attribute__((ext_vector_type(8)))  short bf16x8;
typedef __attribute__((ext_vector_type(8)))  short short8_t;

__device__ __forceinline__ unsigned short f2bf(float f) {
    union { float fv; uint32_t u; } c; c.fv = f;
    return (unsigned short)((c.u + 0x7fffu + ((c.u >> 16) & 1u)) >> 16);
}

__device__ __forceinline__ float fexp2(float x) {
#if __has_builtin(__builtin_amdgcn_exp2f)
    return __builtin_amdgcn_exp2f(x);
#else
    return exp2f(x);
#endif
}

__device__ __forceinline__ void gload16(const void* g, char* l) {
    __builtin_amdgcn_global_load_lds(
        (const __attribute__((address_space(1))) void*)g,
        (__attribute__((address_space(3))) void*)l, 16, 0, 0);
}

// P^T f32[16] -> two bf16x8 B-fragments (verified cvt_pk + permlane order)
#define P_TO_FRAGS(P, U0, U1)                                                            \
    {                                                                                    \
        unsigned int wrd[8];                                                             \
        _Pragma("unroll")                                                                \
        for (int j = 0; j < 8; ++j)                                                      \
            asm("v_cvt_pk_bf16_f32 %0, %1, %2" : "=v"(wrd[j]) : "v"(P[2*j]), "v"(P[2*j+1])); \
        asm("v_permlane32_swap_b32 %0, %1" : "+v"(wrd[0]), "+v"(wrd[2]));                \
        asm("v_permlane32_swap_b32 %0, %1" : "+v"(wrd[1]), "+v"(wrd[3]));                \
        asm("v_permlane32_swap_b32 %0, %1" : "+v"(wrd[4]), "+v"(wrd[6]));                \
        asm("v_permlane32_swap_b32 %0, %1" : "+v"(wrd[5]), "+v"(wrd[7]));                \
        U0.u[0] = wrd[0]; U0.u[1] = wrd[1]; U0.u[2] = wrd[2]; U0.u[3] = wrd[3];          \
        U1.u[0] = wrd[4]; U1.u[1] = wrd[5]; U1.u[2] = wrd[6]; U1.u[3] = wrd[7];          \
    }

// ---- fused prepass: K fp32->bf16 + V transpose (64 seq rows per block) ----
__global__ __launch_bounds__(256)
void prep_kv(const float* __restrict__ K, const float* __restrict__ V,
             unsigned short* __restrict__ Kb, unsigned short* __restrict__ Vt) {
    __shared__ float tile[64][65];
    const int h  = blockIdx.y;
    const int s0 = blockIdx.x * 64;
    const int tid = threadIdx.x;
    const size_t hb = (size_t)h * kS * kD;

    {
        const size_t base = hb + (size_t)s0 * kD + (size_t)tid * 16;
        float4_t a = *(const float4_t*)(K + base);
        float4_t b = *(const float4_t*)(K + base + 4);
        float4_t c = *(const float4_t*)(K + base + 8);
        float4_t d = *(const float4_t*)(K + base + 12);
        short8_t o0, o1;
        #pragma unroll
        for (int j = 0; j < 4; ++j) {
            o0[j] = (short)f2bf(a[j]); o0[j + 4] = (short)f2bf(b[j]);
            o1[j] = (short)f2bf(c[j]); o1[j + 4] = (short)f2bf(d[j]);
        }
        *(short8_t*)(Kb + base)     = o0;
        *(short8_t*)(Kb + base + 8) = o1;
    }

    #pragma unroll
    for (int it = 0; it < 4; ++it) {
        const int n = tid + it * 256;
        const int s = n >> 4, d0 = (n & 15) * 4;
        float4_t v = *(const float4_t*)(V + hb + (size_t)(s0 + s) * kD + d0);
        tile[s][d0 + 0] = v[0]; tile[s][d0 + 1] = v[1];
        tile[s][d0 + 2] = v[2]; tile[s][d0 + 3] = v[3];
    }
    __syncthreads();
    #pragma unroll
    for (int it = 0; it < 2; ++it) {
        const int n = tid + it * 256;
        const int d = n >> 3, sc = (n & 7) * 8;
        short8_t o;
        #pragma unroll
        for (int j = 0; j < 8; ++j) o[j] = (short)f2bf(tile[sc + j][d]);
        *(short8_t*)(Vt + (size_t)h * kD * kS + (size_t)d * kS + s0 + sc) = o;
    }
}

// ---- main: R6 skeleton + straight-line fused fast path for interior tiles ----
__global__ __launch_bounds__(256, 4)
void swa_main(const float* __restrict__ Qg, const unsigned short* __restrict__ Kb,
              const unsigned short* __restrict__ Vt, float* __restrict__ Og) {
    __shared__ __align__(16) char lds[2][16384];

    const int lid  = blockIdx.x;                      // 0..1023
    const int swz  = (lid & 7) * 128 + (lid >> 3);    // XCD-chunked, bijective
    const int h    = swz >> 6;
    const int qblk = swz & 63;

    const int tid  = threadIdx.x;
    const int wv   = tid >> 6;
    const int lane = tid & 63;
    const int lq   = lane & 31;
    const int hi   = lane >> 5;

    const int q0b = qblk * 128;
    const int qs  = q0b + wv * 32;
    const int q   = qs + lq;
    const size_t hb  = (size_t)h * kS * kD;
    const size_t hbv = (size_t)h * kD * kS;

    constexpr float qscale = 0.125f * 1.44269504f;
    bf16x8 qf[4];
    {
        const float* qp = Qg + hb + (size_t)q * kD + hi * 8;
        #pragma unroll
        for (int c = 0; c < 4; ++c) {
            float4_t a = *(const float4_t*)(qp + c * 16);
            float4_t b = *(const float4_t*)(qp + c * 16 + 4);
            bf16x8 f;
            #pragma unroll
            for (int j = 0; j < 4; ++j) {
                f[j]     = (short)f2bf(a[j] * qscale);
                f[j + 4] = (short)f2bf(b[j] * qscale);
            }
            qf[c] = f;
        }
    }

    f32x16 acc[2];
    #pragma unroll
    for (int r = 0; r < 16; ++r) { acc[0][r] = 0.f; acc[1][r] = 0.f; }
    float l4[4] = {0.f, 0.f, 0.f, 0.f};

    const int kstart = (q0b >= kW) ? q0b - kW : 0;
    const int nt     = (q0b + 128 - kstart) >> 6;

    int srcK[2], srcV[2];
    #pragma unroll
    for (int i = 0; i < 2; ++i) {
        const int n = tid + i * 256;
        const int c = n ^ ((n >> 3) & 7);
        srcK[i] = (c >> 3) * 64 + (c & 7) * 8;
        srcV[i] = (c >> 3) * kS + (c & 7) * 8;
    }
    const unsigned short* KbH = Kb + hb;
    const unsigned short* VtH = Vt + hbv;

    auto stage = [&](int buf, int kb) {
        const unsigned short* Kt = KbH + (size_t)kb * 64;
        const unsigned short* Vq = VtH + kb;
        #pragma unroll
        for (int i = 0; i < 2; ++i) {
            const int db = i * 4096 + wv * 1024;
            gload16(Kt + srcK[i], &lds[buf][db]);
            gload16(Vq + srcV[i], &lds[buf][8192 + db]);
        }
    };

    union U { unsigned int u[4]; bf16x8 v; };

    stage(0, kstart);
    for (int t = 0; t < nt; ++t) {
        const int kb  = kstart + t * 64;
        const int kbn = (t + 1 < nt) ? kb + 64 : kb;
        stage((t + 1) & 1, kbn);
        asm volatile("s_waitcnt vmcnt(4)" ::: "memory");
        __builtin_amdgcn_s_barrier();
        asm volatile("" ::: "memory");

        const char* Kl = lds[t & 1];
        const char* Vl = lds[t & 1] + 8192;
        const int ksw = (lq & 7) << 4;

        const bool fast = (kb >= qs - 992) && (kb + 32 <= qs - 32);  // both halves interior

        if (fast) {
            // ---- straight-line fused both-halves path (no masks, no branches) ----
            bf16x8 kf0[4], kf1[4], vf0[4], vf1[4];
            #pragma unroll
            for (int c = 0; c < 4; ++c) {
                kf0[c] = *(const bf16x8*)(Kl + ((lq * 128        + c * 32 + hi * 16) ^ ksw));
                kf1[c] = *(const bf16x8*)(Kl + (((32 + lq) * 128 + c * 32 + hi * 16) ^ ksw));
            }
            #pragma unroll
            for (int dh = 0; dh < 2; ++dh)
                #pragma unroll
                for (int kc = 0; kc < 2; ++kc) {
                    vf0[dh * 2 + kc] = *(const bf16x8*)(
                        Vl + (((dh * 32 + lq) * 128 + kc * 32 + hi * 16) ^ ksw));
                    vf1[dh * 2 + kc] = *(const bf16x8*)(
                        Vl + (((dh * 32 + lq) * 128 + 64 + kc * 32 + hi * 16) ^ ksw));
                }

            f32x16 st0, st1;
            #pragma unroll
            for (int r = 0; r < 16; ++r) { st0[r] = 0.f; st1[r] = 0.f; }
            #pragma unroll
            for (int c = 0; c < 4; ++c) {
                st0 = __builtin_amdgcn_mfma_f32_32x32x16_bf16(kf0[c], qf[c], st0, 0, 0, 0);
                st1 = __builtin_amdgcn_mfma_f32_32x32x16_bf16(kf1[c], qf[c], st1, 0, 0, 0);
            }

            float p0[16], p1[16];
            #pragma unroll
            for (int r = 0; r < 16; ++r) { p0[r] = fexp2(st0[r]); p1[r] = fexp2(st1[r]); }
            #pragma unroll
            for (int r = 0; r < 16; ++r) l4[r & 3] += p0[r] + p1[r];

            U a00, a01, a10, a11;
            P_TO_FRAGS(p0, a00, a01);
            P_TO_FRAGS(p1, a10, a11);

            acc[0] = __builtin_amdgcn_mfma_f32_32x32x16_bf16(vf0[0], a00.v, acc[0], 0, 0, 0);
            acc[1] = __builtin_amdgcn_mfma_f32_32x32x16_bf16(vf0[2], a00.v, acc[1], 0, 0, 0);
            acc[0] = __builtin_amdgcn_mfma_f32_32x32x16_bf16(vf0[1], a01.v, acc[0], 0, 0, 0);
            acc[1] = __builtin_amdgcn_mfma_f32_32x32x16_bf16(vf0[3], a01.v, acc[1], 0, 0, 0);
            acc[0] = __builtin_amdgcn_mfma_f32_32x32x16_bf16(vf1[0], a10.v, acc[0], 0, 0, 0);
            acc[1] = __builtin_amdgcn_mfma_f32_32x32x16_bf16(vf1[2], a10.v, acc[1], 0, 0, 0);
            acc[0] = __builtin_amdgcn_mfma_f32_32x32x16_bf16(vf1[1], a11.v, acc[0], 0, 0, 0);
            acc[1] = __builtin_amdgcn_mfma_f32_32x32x16_bf16(vf1[3], a11.v, acc[1], 0, 0, 0);
        } else {
            // ---- edge path: per-half guarded + masked (R6-verified) ----
            #pragma unroll
            for (int half = 0; half < 2; ++half) {
                const int kh = kb + half * 32;
                if (kh <= qs && kh >= qs - kW) {
                    const int krow = half * 32 + lq;
                    bf16x8 kf[4];
                    #pragma unroll
                    for (int c = 0; c < 4; ++c)
                        kf[c] = *(const bf16x8*)(Kl + ((krow * 128 + c * 32 + hi * 16) ^ ksw));

                    f32x16 st;
                    #pragma unroll
                    for (int r = 0; r < 16; ++r) st[r] = 0.f;
                    __builtin_amdgcn_s_setprio(1);
                    #pragma unroll
                    for (int c = 0; c < 4; ++c)
                        st = __builtin_amdgcn_mfma_f32_32x32x16_bf16(kf[c], qf[c], st, 0, 0, 0);
                    __builtin_amdgcn_s_setprio(0);

                    bf16x8 vf[4];
                    #pragma unroll
                    for (int dh = 0; dh < 2; ++dh)
                        #pragma unroll
                        for (int kc = 0; kc < 2; ++kc)
                            vf[dh * 2 + kc] = *(const bf16x8*)(
                                Vl + (((dh * 32 + lq) * 128 + half * 64 + kc * 32 + hi * 16) ^ ksw));

                    float p[16];
                    #pragma unroll
                    for (int r = 0; r < 16; ++r) {
                        const int ki = kh + (r & 3) + 8 * (r >> 2) + 4 * hi;
                        const bool ok = (ki <= q) && (ki + kW >= q);
                        const float e = fexp2(st[r]);
                        p[r] = ok ? e : 0.f;
                    }
                    #pragma unroll
                    for (int r = 0; r < 16; ++r) l4[r & 3] += p[r];

                    U u0, u1;
                    P_TO_FRAGS(p, u0, u1);

                    __builtin_amdgcn_s_setprio(1);
                    acc[0] = __builtin_amdgcn_mfma_f32_32x32x16_bf16(vf[0], u0.v, acc[0], 0, 0, 0);
                    acc[1] = __builtin_amdgcn_mfma_f32_32x32x16_bf16(vf[2], u0.v, acc[1], 0, 0, 0);
                    acc[0] = __builtin_amdgcn_mfma_f32_32x32x16_bf16(vf[1], u1.v, acc[0], 0, 0, 0);
                    acc[1] = __builtin_amdgcn_mfma_f32_32x32x16_bf16(vf[3], u1.v, acc[1], 0, 0, 0);
                    __builtin_amdgcn_s_setprio(0);
                }
            }
        }

        asm volatile("" ::: "memory");
        __builtin_amdgcn_s_barrier();
        asm volatile("" ::: "memory");
    }

    // ---- epilogue ----
    float l = (l4[0] + l4[1]) + (l4[2] + l4[3]);
    l += __shfl_xor(l, 32);
    const float rl = 1.f / l;
    float* op = Og + hb + (size_t)q * kD;
    #pragma unroll
    for (int g = 0; g < 4; ++g) {
        float4_t o0, o1;
        #pragma unroll
        for (int j = 0; j < 4; ++j) {
            o0[j] = acc[0][g * 4 + j] * rl;
            o1[j] = acc[1][g * 4 + j] * rl;
        }
        *(float4_t*)(op + g * 8 + hi * 4)      = o0;
        *(float4_t*)(op + 32 + g * 8 + hi * 4) = o1;
    }
}
} // namespace

extern "C" void kernel_launch(void* const* d_in, const int* in_sizes, int n_in,
                              void* d_out, int out_size, void* d_ws, size_t ws_size,
                              hipStream_t stream) {
    (void)in_sizes; (void)n_in; (void)out_size; (void)ws_size;
    const float* Q = (const float*)d_in[0];
    const float* K = (const float*)d_in[1];
    const float* V = (const float*)d_in[2];
    float* O = (float*)d_out;
    unsigned short* Kb = (unsigned short*)d_ws;
    unsigned short* Vt = Kb + (size_t)kH * kS * kD;

    prep_kv<<<dim3(kS / 64, kH), dim3(256), 0, stream>>>(K, V, Kb, Vt);
    swa_main<<<dim3(1024), dim3(256), 0, stream>>>(Q, Kb, Vt, O);
}